// Round 4
// baseline (741.750 us; speedup 1.0000x reference)
//
#include <hip/hip_runtime.h>
#include <hip/hip_bf16.h>
#include <cstdint>
#include <cstddef>

#define MROWS 100352   // B*H*W = 32*56*56
#define CDIM  512
#define HDIM  2048

typedef __attribute__((ext_vector_type(8))) short   short8;
typedef __attribute__((ext_vector_type(8))) __bf16  bf16x8;
typedef __attribute__((ext_vector_type(4))) __bf16  bf16x4;
typedef __attribute__((ext_vector_type(4))) float   floatx4;

static __device__ __forceinline__ unsigned short f2bf(float f) {
  union { float f; unsigned int u; } c; c.f = f;
  unsigned int u = c.u;
  return (unsigned short)((u + 0x7FFFu + ((u >> 16) & 1u)) >> 16);  // RNE
}

static __device__ __forceinline__ void gload_lds16(const void* g, void* l) {
  __builtin_amdgcn_global_load_lds(
      (const __attribute__((address_space(1))) void*)g,
      (__attribute__((address_space(3))) void*)l, 16, 0, 0);
}

#define BAR()   asm volatile("s_barrier" ::: "memory")
#define LGKM0() asm volatile("s_waitcnt lgkmcnt(0)" ::: "memory")
#define VMC6()  asm volatile("s_waitcnt vmcnt(6)" ::: "memory")
#define VMC4()  asm volatile("s_waitcnt vmcnt(4)" ::: "memory")
#define VMC0()  asm volatile("s_waitcnt vmcnt(0)" ::: "memory")

// ---- cast both MLP weight matrices fp32 -> bf16 -------------------------
__global__ void cast_weights(const float4* __restrict__ s1, unsigned short* __restrict__ d1,
                             const float4* __restrict__ s2, unsigned short* __restrict__ d2) {
  int t = blockIdx.x * 256 + threadIdx.x;
  const int N4 = (HDIM * CDIM) / 4;
  const float4* s; unsigned short* d; int idx;
  if (t < N4) { s = s1; d = d1; idx = t; }
  else        { s = s2; d = d2; idx = t - N4; }
  float4 f = s[idx];
  ushort4 u = make_ushort4(f2bf(f.x), f2bf(f.y), f2bf(f.z), f2bf(f.w));
  *reinterpret_cast<ushort4*>(d + (size_t)idx * 4) = u;
}

// ---- LayerNorm over C=512 + cast to bf16, one wave per row --------------
__global__ void ln_cast(const float* __restrict__ x, const float* __restrict__ g,
                        const float* __restrict__ b, unsigned short* __restrict__ xn) {
  const int row  = blockIdx.x * 4 + (threadIdx.x >> 6);
  const int lane = threadIdx.x & 63;
  const float4* xr = reinterpret_cast<const float4*>(x + (size_t)row * CDIM);
  const float4 v0 = xr[lane], v1 = xr[lane + 64];
  float s  = v0.x + v0.y + v0.z + v0.w + v1.x + v1.y + v1.z + v1.w;
  float ss = v0.x*v0.x + v0.y*v0.y + v0.z*v0.z + v0.w*v0.w
           + v1.x*v1.x + v1.y*v1.y + v1.z*v1.z + v1.w*v1.w;
#pragma unroll
  for (int o = 1; o < 64; o <<= 1) { s += __shfl_xor(s, o); ss += __shfl_xor(ss, o); }
  const float mean = s * (1.0f / CDIM);
  const float rstd = rsqrtf(ss * (1.0f / CDIM) - mean * mean + 1e-5f);
  const float4* g4 = reinterpret_cast<const float4*>(g);
  const float4* b4 = reinterpret_cast<const float4*>(b);
  const float4 ga = g4[lane], gb = g4[lane + 64];
  const float4 ba = b4[lane], bb = b4[lane + 64];
  ushort4 o0 = make_ushort4(
      f2bf((v0.x - mean) * rstd * ga.x + ba.x),
      f2bf((v0.y - mean) * rstd * ga.y + ba.y),
      f2bf((v0.z - mean) * rstd * ga.z + ba.z),
      f2bf((v0.w - mean) * rstd * ga.w + ba.w));
  ushort4 o1 = make_ushort4(
      f2bf((v1.x - mean) * rstd * gb.x + bb.x),
      f2bf((v1.y - mean) * rstd * gb.y + bb.y),
      f2bf((v1.z - mean) * rstd * gb.z + bb.z),
      f2bf((v1.w - mean) * rstd * gb.w + bb.w));
  unsigned short* orow = xn + (size_t)row * CDIM;
  *reinterpret_cast<ushort4*>(orow + lane * 4)        = o0;
  *reinterpret_cast<ushort4*>(orow + (lane + 64) * 4) = o1;
}

// ---- GEMM1: 256x256-tile 8-phase (verified round-3 structure) -----------
// C = A(MxK) * Bw(NxK)^T, swapped-operand 16x16x32 MFMA, balanced XOR
// swizzle, quadrant schedule + counted vmcnt, XCD swizzle.
// out = bf16(gelu_sigmoid(acc + bias[n])), ldc=NDIM
template<int KDIM, int NDIM>
__global__ __launch_bounds__(512, 2) void gemm256(
    const unsigned short* __restrict__ A, const unsigned short* __restrict__ Bw,
    const float* __restrict__ bias, void* __restrict__ Cout) {
  __shared__ __align__(16) unsigned short sm[2][2][2][8192];

  const int tid  = threadIdx.x;
  const int lane = tid & 63, w = tid >> 6;
  const int swr = w >> 2, swc = w & 3;           // wave 2x4 grid
  const int frow = tid & 15, fk = ((tid & 63) >> 4) * 8;

  constexpr int GX = NDIM / 256;
  const int nwg = gridDim.x;
  const int lid = ((int)blockIdx.x & 7) * (nwg >> 3) + ((int)blockIdx.x >> 3);
  const int m0 = (lid / GX) * 256, n0 = (lid % GX) * 256;

  const size_t ldb = (size_t)KDIM * 2;
  const int srow = tid >> 3;
  const int scb  = ((tid ^ (tid >> 3)) & 7) * 16;
  const char* gA = (const char*)A  + (size_t)(m0 + srow) * ldb + scb;
  const char* gB = (const char*)Bw + (size_t)(n0 + srow) * ldb + scb;

  auto STG = [&](const char* gbase, int tile, int half, int isB) {
    unsigned short* hb = &sm[isB][tile & 1][half][0];
    const char* s = gbase + (size_t)half * 128 * ldb + (size_t)tile * 128;
    gload_lds16(s,            hb + w * 512);
    gload_lds16(s + 64 * ldb, hb + 4096 + w * 512);
  };
  auto LDA = [&](bf16x8* a, int db, int qm) {
#pragma unroll
    for (int mi = 0; mi < 4; ++mi)
#pragma unroll
      for (int kk = 0; kk < 2; ++kk) {
        const int row = swr * 64 + mi * 16 + frow;
        const int col = kk * 32 + fk;
        const int sidx = row * 64 + (col ^ ((row & 7) << 3));
        a[mi * 2 + kk] = __builtin_bit_cast(bf16x8,
            *reinterpret_cast<const short8*>(&sm[0][db][qm][sidx]));
      }
  };
  auto LDBf = [&](bf16x8* b, int db, int qn) {
#pragma unroll
    for (int nj = 0; nj < 2; ++nj)
#pragma unroll
      for (int kk = 0; kk < 2; ++kk) {
        const int row = swc * 32 + nj * 16 + frow;
        const int col = kk * 32 + fk;
        const int sidx = row * 64 + (col ^ ((row & 7) << 3));
        b[nj * 2 + kk] = __builtin_bit_cast(bf16x8,
            *reinterpret_cast<const short8*>(&sm[1][db][qn][sidx]));
      }
  };

  floatx4 acc[2][2][4][2] = {};
  auto MM = [&](floatx4 (*a2)[2], const bf16x8* a, const bf16x8* b) {
    __builtin_amdgcn_s_setprio(1);
#pragma unroll
    for (int mi = 0; mi < 4; ++mi)
#pragma unroll
      for (int nj = 0; nj < 2; ++nj)
#pragma unroll
        for (int kk = 0; kk < 2; ++kk)
          a2[mi][nj] = __builtin_amdgcn_mfma_f32_16x16x32_bf16(
              b[nj * 2 + kk], a[mi * 2 + kk], a2[mi][nj], 0, 0, 0);
    __builtin_amdgcn_s_setprio(0);
  };

  constexpr int nt = KDIM / 64;

  STG(gA, 0, 0, 0); STG(gB, 0, 0, 1);
  STG(gA, 0, 1, 0); STG(gB, 0, 1, 1);
  STG(gA, 1, 0, 0); STG(gB, 1, 0, 1);
  VMC4();
  BAR();

  for (int t2 = 0; t2 < nt; ++t2) {
    const int db = t2 & 1;
    bf16x8 a[8], b0[4], b1[4];

    LDA(a, db, 0); LDBf(b0, db, 0);
    if (t2 + 1 < nt) STG(gA, t2 + 1, 1, 0);
    BAR(); LGKM0();
    MM(acc[0][0], a, b0);
    BAR();

    LDBf(b1, db, 1);
    if (t2 + 1 < nt) STG(gB, t2 + 1, 1, 1);
    BAR(); LGKM0();
    MM(acc[0][1], a, b1);
    BAR();

    LDA(a, db, 1);
    if (t2 + 2 < nt) STG(gA, t2 + 2, 0, 0);
    BAR(); LGKM0();
    MM(acc[1][0], a, b0);
    BAR();

    if (t2 + 2 < nt) STG(gB, t2 + 2, 0, 1);
    BAR(); LGKM0();
    MM(acc[1][1], a, b1);
    if (t2 < nt - 2)       { VMC4(); }
    else if (t2 == nt - 2) { VMC0(); }
    BAR();
  }

  const int em = lane & 15;
  const int en = (lane >> 4) << 2;

  float4 bj[4];
#pragma unroll
  for (int qn = 0; qn < 2; ++qn)
#pragma unroll
    for (int nj = 0; nj < 2; ++nj)
      bj[qn * 2 + nj] = *reinterpret_cast<const float4*>(
          &bias[n0 + qn * 128 + swc * 32 + nj * 16 + en]);

#pragma unroll
  for (int qm = 0; qm < 2; ++qm)
#pragma unroll
    for (int mi = 0; mi < 4; ++mi) {
      const int gm = m0 + qm * 128 + swr * 64 + mi * 16 + em;
      const size_t rowoff = (size_t)gm * NDIM + n0 + swc * 32 + en;
#pragma unroll
      for (int qn = 0; qn < 2; ++qn)
#pragma unroll
        for (int nj = 0; nj < 2; ++nj) {
          const float4 bb = bj[qn * 2 + nj];
          const floatx4 av = acc[qm][qn][mi][nj];
          float v0 = av[0] + bb.x, v1 = av[1] + bb.y;
          float v2 = av[2] + bb.z, v3 = av[3] + bb.w;
          const size_t off = rowoff + qn * 128 + nj * 16;
          v0 *= __builtin_amdgcn_rcpf(1.0f + __expf(-1.702f * v0));
          v1 *= __builtin_amdgcn_rcpf(1.0f + __expf(-1.702f * v1));
          v2 *= __builtin_amdgcn_rcpf(1.0f + __expf(-1.702f * v2));
          v3 *= __builtin_amdgcn_rcpf(1.0f + __expf(-1.702f * v3));
          bf16x4 o = { (__bf16)v0, (__bf16)v1, (__bf16)v2, (__bf16)v3 };
          *reinterpret_cast<bf16x4*>((unsigned short*)Cout + off) = o;
        }
    }
}

// ---- GEMM2: 256x128-tile, 2-phase counted-vmcnt schedule ----------------
// C = A(Mx2048) * Bw(512x2048)^T + bias + resid -> f32, grid 1568 (87.5% util)
// 8 waves 4Mx2N (wave 64x64), BK=64, LDS 96KB (A 2x32KB + B 2x16KB).
// Per t2: {16 ds_read frags; BAR; stage t+2 (6 gloads, current buf — dead
// after BAR); setprio MFMA x32; vmcnt(6); BAR}. vmcnt(6) = t+1's 6 in
// flight, guarantees own t+1 landed; BAR publishes across waves.
__global__ __launch_bounds__(512, 2) void gemm_k2(
    const unsigned short* __restrict__ A, const unsigned short* __restrict__ Bw,
    const float* __restrict__ bias, const float* __restrict__ resid,
    float* __restrict__ Cout) {
  __shared__ __align__(16) unsigned short smA[2][16384];  // 256 x 64
  __shared__ __align__(16) unsigned short smB[2][8192];   // 128 x 64

  const int tid  = threadIdx.x;
  const int lane = tid & 63, w = tid >> 6;
  const int swr = w >> 1, swc = w & 1;           // wave 4x2 grid, 64x64 tile
  const int frow = lane & 15, fk = (lane >> 4) * 8;

  const int nwg = gridDim.x;                     // 1568 = 8*196
  const int lid = ((int)blockIdx.x & 7) * (nwg >> 3) + ((int)blockIdx.x >> 3);
  const int m0 = (lid >> 2) * 256, n0 = (lid & 3) * 128;

  const size_t ldb = (size_t)HDIM * 2;
  const int srow = tid >> 3;
  const int scb  = ((tid ^ (tid >> 3)) & 7) * 16;
  const char* gA = (const char*)A  + (size_t)(m0 + srow) * ldb + scb;
  const char* gB = (const char*)Bw + (size_t)(n0 + srow) * ldb + scb;

  auto STG = [&](int t) {
    const int db = t & 1;
    const char* sa = gA + (size_t)t * 128;
    const char* sb = gB + (size_t)t * 128;
    gload_lds16(sa,             &smA[db][0]     + w * 512);
    gload_lds16(sa +  64 * ldb, &smA[db][4096]  + w * 512);
    gload_lds16(sa + 128 * ldb, &smA[db][8192]  + w * 512);
    gload_lds16(sa + 192 * ldb, &smA[db][12288] + w * 512);
    gload_lds16(sb,             &smB[db][0]     + w * 512);
    gload_lds16(sb +  64 * ldb, &smB[db][4096]  + w * 512);
  };

  floatx4 acc[4][4] = {};   // [mi][nj]

  STG(0); STG(1);
  VMC6();
  BAR();

  constexpr int nt = HDIM / 64;   // 32
  for (int t = 0; t < nt; ++t) {
    const int db = t & 1;
    bf16x8 a[8], b[8];
#pragma unroll
    for (int mi = 0; mi < 4; ++mi)
#pragma unroll
      for (int kk = 0; kk < 2; ++kk) {
        const int row = swr * 64 + mi * 16 + frow;
        const int col = kk * 32 + fk;
        const int sidx = row * 64 + (col ^ ((row & 7) << 3));
        a[mi * 2 + kk] = __builtin_bit_cast(bf16x8,
            *reinterpret_cast<const short8*>(&smA[db][sidx]));
      }
#pragma unroll
    for (int nj = 0; nj < 4; ++nj)
#pragma unroll
      for (int kk = 0; kk < 2; ++kk) {
        const int row = swc * 64 + nj * 16 + frow;
        const int col = kk * 32 + fk;
        const int sidx = row * 64 + (col ^ ((row & 7) << 3));
        b[nj * 2 + kk] = __builtin_bit_cast(bf16x8,
            *reinterpret_cast<const short8*>(&smB[db][sidx]));
      }
    BAR();                        // all waves done reading buf db
    if (t + 2 < nt) STG(t + 2);   // into buf db (dead per BAR above)
    __builtin_amdgcn_s_setprio(1);
#pragma unroll
    for (int mi = 0; mi < 4; ++mi)
#pragma unroll
      for (int nj = 0; nj < 4; ++nj)
#pragma unroll
        for (int kk = 0; kk < 2; ++kk)   // swapped operands
          acc[mi][nj] = __builtin_amdgcn_mfma_f32_16x16x32_bf16(
              b[nj * 2 + kk], a[mi * 2 + kk], acc[mi][nj], 0, 0, 0);
    __builtin_amdgcn_s_setprio(0);
    if (t + 2 < nt)       { VMC6(); }   // t+1 landed, t+2 stays in flight
    else if (t + 2 == nt) { VMC0(); }   // final prefetch drain
    BAR();
  }

  // epilogue (swapped layout): gm = ...+lane&15, gn = ...+(lane>>4)*4 + r
  const int em = lane & 15;
  const int en = (lane >> 4) << 2;

  float4 bj[4];
#pragma unroll
  for (int nj = 0; nj < 4; ++nj)
    bj[nj] = *reinterpret_cast<const float4*>(&bias[n0 + swc * 64 + nj * 16 + en]);

#pragma unroll
  for (int mi = 0; mi < 4; ++mi) {
    const int gm = m0 + swr * 64 + mi * 16 + em;
    const size_t rowoff = (size_t)gm * CDIM + n0 + swc * 64 + en;
#pragma unroll
    for (int nj = 0; nj < 4; ++nj) {
      const float4 bb = bj[nj];
      const floatx4 av = acc[mi][nj];
      const size_t off = rowoff + nj * 16;
      const float4 r4 = *reinterpret_cast<const float4*>(resid + off);
      float4 o = make_float4(av[0] + bb.x + r4.x, av[1] + bb.y + r4.y,
                             av[2] + bb.z + r4.z, av[3] + bb.w + r4.w);
      *reinterpret_cast<float4*>(Cout + off) = o;
    }
  }
}

extern "C" void kernel_launch(void* const* d_in, const int* in_sizes, int n_in,
                              void* d_out, int out_size, void* d_ws, size_t ws_size,
                              hipStream_t stream) {
  // input order: x wqkv bqkv wo bo g1 b1 g2 b2 w_mlp1 b_mlp1 w_mlp2 b_mlp2
  const float* x   = (const float*)d_in[0];
  const float* g2  = (const float*)d_in[7];
  const float* b2  = (const float*)d_in[8];
  const float* w1  = (const float*)d_in[9];
  const float* b1  = (const float*)d_in[10];
  const float* w2  = (const float*)d_in[11];
  const float* b2m = (const float*)d_in[12];
  float* out = (float*)d_out;

  // Output is exactly x + MLP(LN(x,g2,b2)) — the attention branch of the
  // reference is discarded (xr == x after the two opposite rolls).

  // workspace: w1b (2MB bf16) | w2b (2MB bf16) | G (411MB bf16)
  unsigned short* w1b = (unsigned short*)d_ws;
  unsigned short* w2b = w1b + (size_t)HDIM * CDIM;
  unsigned short* G   = w2b + (size_t)HDIM * CDIM;
  // LN output (bf16, 103MB) parked in d_out; consumed by GEMM1 before GEMM2
  // overwrites d_out with the final result (stream-ordered).
  unsigned short* xn = (unsigned short*)d_out;

  cast_weights<<<2048, 256, 0, stream>>>((const float4*)w1, w1b, (const float4*)w2, w2b);
  ln_cast<<<MROWS / 4, 256, 0, stream>>>(x, g2, b2, xn);

  // gemm1: (M x 512) * (2048 x 512)^T -> gelu -> bf16 G ; grid 3136 (%8==0)
  gemm256<CDIM, HDIM><<<dim3((HDIM / 256) * (MROWS / 256)), 512, 0, stream>>>(
      xn, w1b, b1, (void*)G);
  // gemm2: (M x 2048) * (512 x 2048)^T + bias + x -> f32 out ; grid 1568 (%8==0)
  gemm_k2<<<dim3((CDIM / 128) * (MROWS / 256)), 512, 0, stream>>>(
      G, w2b, b2m, x, out);
}